// Round 1
// baseline (2273.624 us; speedup 1.0000x reference)
//
#include <hip/hip_runtime.h>
#include <stdint.h>

#define NN 100000
#define NE 1600000
#define NG 1000

// ---------------- degree / dinv ----------------
__global__ void k_deg(const int* __restrict__ col, int* __restrict__ cnt) {
    int e = blockIdx.x * 256 + threadIdx.x;
    if (e < NE) atomicAdd(&cnt[col[e]], 1);
}

__global__ void k_dinv(const int* __restrict__ cnt, float* __restrict__ dinv) {
    int n = blockIdx.x * 256 + threadIdx.x;
    if (n < NN) dinv[n] = 1.0f / sqrtf((float)cnt[n] + 2.0f);
}

// ---------------- prefix scans for CSR ----------------
__global__ void k_scan1(const int* __restrict__ cnt, int* __restrict__ csum) {
    __shared__ int s[256];
    int i = blockIdx.x * 256 + threadIdx.x;
    s[threadIdx.x] = (i < NN) ? cnt[i] : 0;
    __syncthreads();
    for (int o = 128; o > 0; o >>= 1) {
        if (threadIdx.x < o) s[threadIdx.x] += s[threadIdx.x + o];
        __syncthreads();
    }
    if (threadIdx.x == 0) csum[blockIdx.x] = s[0];
}

__global__ void k_scan2(const int* __restrict__ csum, int* __restrict__ csum2, int nb) {
    __shared__ int s[512];
    int t = threadIdx.x;
    int v = (t < nb) ? csum[t] : 0;
    s[t] = v; __syncthreads();
    for (int o = 1; o < 512; o <<= 1) {
        int x = (t >= o) ? s[t - o] : 0;
        __syncthreads();
        s[t] += x;
        __syncthreads();
    }
    if (t < nb) csum2[t] = s[t] - v;  // exclusive
}

__global__ void k_scan3(const int* __restrict__ cnt, const int* __restrict__ csum2,
                        int* __restrict__ indptr) {
    __shared__ int s[256];
    int t = threadIdx.x;
    int i = blockIdx.x * 256 + t;
    int v = (i < NN) ? cnt[i] : 0;
    s[t] = v; __syncthreads();
    for (int o = 1; o < 256; o <<= 1) {
        int x = (t >= o) ? s[t - o] : 0;
        __syncthreads();
        s[t] += x;
        __syncthreads();
    }
    if (i < NN) indptr[i] = csum2[blockIdx.x] + s[t] - v;
    if (i == 0) indptr[NN] = NE;
}

__global__ void k_scatter(const int* __restrict__ row, const int* __restrict__ col,
                          const float* __restrict__ dinv, const int* __restrict__ indptr,
                          int* __restrict__ fill, int* __restrict__ esrc,
                          float* __restrict__ ew) {
    int e = blockIdx.x * 256 + threadIdx.x;
    if (e >= NE) return;
    int r = row[e], c = col[e];
    int pos = indptr[c] + atomicAdd(&fill[c], 1);
    esrc[pos] = r;
    ew[pos] = dinv[r] * dinv[c];
}

// ---------------- fp32 GEMM: out[M x 100] = A[M x K] @ W[K x 100] ----------------
__global__ __launch_bounds__(256) void k_gemm(const float* __restrict__ A,
                                              const float* __restrict__ W,
                                              float* __restrict__ out, int M, int K) {
    __shared__ float As[64][33];
    __shared__ float Ws[32][128];
    int t = threadIdx.x;
    int tr = t & 15;   // row group: rows tr*4 .. tr*4+3 (fastest in wave -> free LDS access)
    int tc = t >> 4;   // col group: cols tc*8 .. tc*8+7
    int rowbase = blockIdx.x * 64;
    float acc[4][8];
#pragma unroll
    for (int i = 0; i < 4; i++)
#pragma unroll
        for (int j = 0; j < 8; j++) acc[i][j] = 0.f;

    for (int k0 = 0; k0 < K; k0 += 32) {
#pragma unroll
        for (int i = 0; i < 8; i++) {
            int e = t + i * 256;
            int r = e >> 5, kk = e & 31;
            int gr = rowbase + r, gk = k0 + kk;
            As[r][kk] = (gr < M && gk < K) ? A[(size_t)gr * K + gk] : 0.f;
        }
#pragma unroll
        for (int i = 0; i < 16; i++) {
            int e = t + i * 256;
            int kr = e >> 7, c = e & 127;
            int gk = k0 + kr;
            Ws[kr][c] = (c < 100 && gk < K) ? W[gk * 100 + c] : 0.f;
        }
        __syncthreads();
#pragma unroll
        for (int kk = 0; kk < 32; kk++) {
            float a[4], w[8];
#pragma unroll
            for (int i = 0; i < 4; i++) a[i] = As[tr * 4 + i][kk];
#pragma unroll
            for (int j = 0; j < 8; j++) w[j] = Ws[kk][tc * 8 + j];
#pragma unroll
            for (int i = 0; i < 4; i++)
#pragma unroll
                for (int j = 0; j < 8; j++) acc[i][j] += a[i] * w[j];
        }
        __syncthreads();
    }

    int c0 = tc * 8;
#pragma unroll
    for (int i = 0; i < 4; i++) {
        int gr = rowbase + tr * 4 + i;
        if (gr >= M) continue;
        if (c0 + 8 <= 100) {
            *(float4*)(&out[(size_t)gr * 100 + c0]) =
                make_float4(acc[i][0], acc[i][1], acc[i][2], acc[i][3]);
            *(float4*)(&out[(size_t)gr * 100 + c0 + 4]) =
                make_float4(acc[i][4], acc[i][5], acc[i][6], acc[i][7]);
        } else if (c0 < 100) {  // c0 == 96
            *(float4*)(&out[(size_t)gr * 100 + c0]) =
                make_float4(acc[i][0], acc[i][1], acc[i][2], acc[i][3]);
        }
    }
}

// ---------------- aggregation: h[n] = relu(sum_e w*xw[src] + 2*dinv^2*xw[n] + b) ----
__global__ __launch_bounds__(256) void k_agg(const float* __restrict__ xw,
                                             const int* __restrict__ indptr,
                                             const int* __restrict__ esrc,
                                             const float* __restrict__ ew,
                                             const float* __restrict__ dinv,
                                             const float* __restrict__ bias,
                                             float* __restrict__ hout) {
    int wave = threadIdx.x >> 6;
    int lane = threadIdx.x & 63;
    int n = blockIdx.x * 4 + wave;
    if (n >= NN) return;
    int beg = indptr[n], end = indptr[n + 1];
    float acc0 = 0.f, acc1 = 0.f;
    for (int e = beg; e < end; e++) {
        int s = esrc[e];
        float w = ew[e];
        const float* xr = xw + (size_t)s * 100;
        acc0 += w * xr[lane];
        if (lane < 36) acc1 += w * xr[64 + lane];
    }
    float di = dinv[n];
    float sw = 2.f * di * di;
    const float* xn = xw + (size_t)n * 100;
    acc0 += sw * xn[lane] + bias[lane];
    hout[(size_t)n * 100 + lane] = fmaxf(acc0, 0.f);
    if (lane < 36) {
        acc1 += sw * xn[64 + lane] + bias[64 + lane];
        hout[(size_t)n * 100 + 64 + lane] = fmaxf(acc1, 0.f);
    }
}

// ---------------- pooling ----------------
__global__ void k_gcount(const int* __restrict__ batch, int* __restrict__ gcnt) {
    int n = blockIdx.x * 256 + threadIdx.x;
    if (n < NN) atomicAdd(&gcnt[batch[n]], 1);
}

__global__ void k_gscan(const int* __restrict__ gcnt, int* __restrict__ gstart) {
    __shared__ int s[1024];
    int t = threadIdx.x;
    int v = (t < NG) ? gcnt[t] : 0;
    s[t] = v; __syncthreads();
    for (int o = 1; o < 1024; o <<= 1) {
        int x = (t >= o) ? s[t - o] : 0;
        __syncthreads();
        s[t] += x;
        __syncthreads();
    }
    if (t < NG) gstart[t] = s[t] - v;
}

__global__ void k_pool(const float* __restrict__ h, const int* __restrict__ gcnt,
                       const int* __restrict__ gstart, float* __restrict__ pooled) {
    int g = blockIdx.x, t = threadIdx.x;
    if (t >= 100) return;
    int cnt = gcnt[g], st = gstart[g];
    float s = 0.f;
    for (int i = 0; i < cnt; i++) s += h[(size_t)(st + i) * 100 + t];
    pooled[g * 100 + t] = s / (float)(cnt > 0 ? cnt : 1);
}

// ---------------- MLP head (fused 3 layers, one block per graph) ----------------
__global__ void k_mlp(const float* __restrict__ pooled,
                      const float* __restrict__ Wl1, const float* __restrict__ bl1,
                      const float* __restrict__ Wl2, const float* __restrict__ bl2,
                      const float* __restrict__ Wl3, const float* __restrict__ bl3,
                      float* __restrict__ out) {
    __shared__ float p[100], q[100];
    int g = blockIdx.x, t = threadIdx.x;
    if (t < 100) p[t] = pooled[g * 100 + t];
    __syncthreads();
    float s1 = 0.f;
    if (t < 100) {
        s1 = bl1[t];
        for (int k = 0; k < 100; k++) s1 += p[k] * Wl1[k * 100 + t];
        s1 = fmaxf(s1, 0.f);
    }
    __syncthreads();
    if (t < 100) q[t] = s1;
    __syncthreads();
    float s2 = 0.f;
    if (t < 100) {
        s2 = bl2[t];
        for (int k = 0; k < 100; k++) s2 += q[k] * Wl2[k * 100 + t];
        s2 = fmaxf(s2, 0.f);
    }
    __syncthreads();
    if (t < 100) p[t] = s2;
    __syncthreads();
    if (t < 29) {
        float s3 = bl3[t];
        for (int k = 0; k < 100; k++) s3 += p[k] * Wl3[k * 29 + t];
        out[g * 29 + t] = s3;
    }
}

// ---------------- launch ----------------
extern "C" void kernel_launch(void* const* d_in, const int* in_sizes, int n_in,
                              void* d_out, int out_size, void* d_ws, size_t ws_size,
                              hipStream_t stream) {
    const float* x     = (const float*)d_in[0];
    const int*   ei    = (const int*)d_in[1];
    const int*   batch = (const int*)d_in[2];
    const float* W1 = (const float*)d_in[3];  const float* b1 = (const float*)d_in[4];
    const float* W2 = (const float*)d_in[5];  const float* b2 = (const float*)d_in[6];
    const float* W3 = (const float*)d_in[7];  const float* b3 = (const float*)d_in[8];
    const float* W4 = (const float*)d_in[9];  const float* b4 = (const float*)d_in[10];
    const float* W5 = (const float*)d_in[11]; const float* b5 = (const float*)d_in[12];
    const float* Wl1 = (const float*)d_in[13]; const float* bl1 = (const float*)d_in[14];
    const float* Wl2 = (const float*)d_in[15]; const float* bl2 = (const float*)d_in[16];
    const float* Wl3 = (const float*)d_in[17]; const float* bl3 = (const float*)d_in[18];
    float* out = (float*)d_out;

    const int* row = ei;
    const int* col = ei + NE;

    // workspace carve-up (256B aligned)
    uintptr_t base = (uintptr_t)d_ws;
    auto alloc = [&](size_t bytes) -> void* {
        void* p = (void*)base;
        base += (bytes + 255) & ~(size_t)255;
        return p;
    };
    int*   degcnt = (int*)alloc(NN * 4);
    float* dinv   = (float*)alloc(NN * 4);
    int*   indptr = (int*)alloc((NN + 1) * 4);
    int*   fill   = (int*)alloc(NN * 4);
    int*   csum   = (int*)alloc(512 * 4);
    int*   csum2  = (int*)alloc(512 * 4);
    int*   gcnt   = (int*)alloc(1024 * 4);
    int*   gstart = (int*)alloc(1024 * 4);
    int*   esrc   = (int*)alloc((size_t)NE * 4);
    float* ew     = (float*)alloc((size_t)NE * 4);
    float* xw     = (float*)alloc((size_t)NN * 100 * 4);
    float* h      = (float*)alloc((size_t)NN * 100 * 4);
    float* pooled = (float*)alloc((size_t)NG * 100 * 4);

    // zero the atomic counters (ws is poisoned 0xAA before every call)
    hipMemsetAsync(degcnt, 0, NN * 4, stream);
    hipMemsetAsync(fill, 0, NN * 4, stream);
    hipMemsetAsync(gcnt, 0, 1024 * 4, stream);

    const int NB = (NN + 255) / 256;  // 391
    k_deg<<<(NE + 255) / 256, 256, 0, stream>>>(col, degcnt);
    k_dinv<<<NB, 256, 0, stream>>>(degcnt, dinv);
    k_scan1<<<NB, 256, 0, stream>>>(degcnt, csum);
    k_scan2<<<1, 512, 0, stream>>>(csum, csum2, NB);
    k_scan3<<<NB, 256, 0, stream>>>(degcnt, csum2, indptr);
    k_scatter<<<(NE + 255) / 256, 256, 0, stream>>>(row, col, dinv, indptr, fill, esrc, ew);

    const int GEMM_GRID = (NN + 63) / 64;  // 1563
    const int AGG_GRID = (NN + 3) / 4;     // 25000

    k_gemm<<<GEMM_GRID, 256, 0, stream>>>(x, W1, xw, NN, 336);
    k_agg<<<AGG_GRID, 256, 0, stream>>>(xw, indptr, esrc, ew, dinv, b1, h);
    k_gemm<<<GEMM_GRID, 256, 0, stream>>>(h, W2, xw, NN, 100);
    k_agg<<<AGG_GRID, 256, 0, stream>>>(xw, indptr, esrc, ew, dinv, b2, h);
    k_gemm<<<GEMM_GRID, 256, 0, stream>>>(h, W3, xw, NN, 100);
    k_agg<<<AGG_GRID, 256, 0, stream>>>(xw, indptr, esrc, ew, dinv, b3, h);
    k_gemm<<<GEMM_GRID, 256, 0, stream>>>(h, W4, xw, NN, 100);
    k_agg<<<AGG_GRID, 256, 0, stream>>>(xw, indptr, esrc, ew, dinv, b4, h);
    k_gemm<<<GEMM_GRID, 256, 0, stream>>>(h, W5, xw, NN, 100);
    k_agg<<<AGG_GRID, 256, 0, stream>>>(xw, indptr, esrc, ew, dinv, b5, h);

    k_gcount<<<NB, 256, 0, stream>>>(batch, gcnt);
    k_gscan<<<1, 1024, 0, stream>>>(gcnt, gstart);
    k_pool<<<NG, 128, 0, stream>>>(h, gcnt, gstart, pooled);
    k_mlp<<<NG, 128, 0, stream>>>(pooled, Wl1, bl1, Wl2, bl2, Wl3, bl3, out);
}

// Round 2
// 1696.518 us; speedup vs baseline: 1.3402x; 1.3402x over previous
//
#include <hip/hip_runtime.h>
#include <stdint.h>

#define NN 100000
#define NE 1600000
#define NG 1000

// ---------------- degree / dinv ----------------
__global__ void k_deg(const int* __restrict__ col, int* __restrict__ cnt) {
    int e = blockIdx.x * 256 + threadIdx.x;
    if (e < NE) atomicAdd(&cnt[col[e]], 1);
}

__global__ void k_dinv(const int* __restrict__ cnt, float* __restrict__ dinv) {
    int n = blockIdx.x * 256 + threadIdx.x;
    if (n < NN) dinv[n] = 1.0f / sqrtf((float)cnt[n] + 2.0f);
}

// ---------------- prefix scans for CSR ----------------
__global__ void k_scan1(const int* __restrict__ cnt, int* __restrict__ csum) {
    __shared__ int s[256];
    int i = blockIdx.x * 256 + threadIdx.x;
    s[threadIdx.x] = (i < NN) ? cnt[i] : 0;
    __syncthreads();
    for (int o = 128; o > 0; o >>= 1) {
        if (threadIdx.x < o) s[threadIdx.x] += s[threadIdx.x + o];
        __syncthreads();
    }
    if (threadIdx.x == 0) csum[blockIdx.x] = s[0];
}

__global__ void k_scan2(const int* __restrict__ csum, int* __restrict__ csum2, int nb) {
    __shared__ int s[512];
    int t = threadIdx.x;
    int v = (t < nb) ? csum[t] : 0;
    s[t] = v; __syncthreads();
    for (int o = 1; o < 512; o <<= 1) {
        int x = (t >= o) ? s[t - o] : 0;
        __syncthreads();
        s[t] += x;
        __syncthreads();
    }
    if (t < nb) csum2[t] = s[t] - v;  // exclusive
}

__global__ void k_scan3(const int* __restrict__ cnt, const int* __restrict__ csum2,
                        int* __restrict__ indptr) {
    __shared__ int s[256];
    int t = threadIdx.x;
    int i = blockIdx.x * 256 + t;
    int v = (i < NN) ? cnt[i] : 0;
    s[t] = v; __syncthreads();
    for (int o = 1; o < 256; o <<= 1) {
        int x = (t >= o) ? s[t - o] : 0;
        __syncthreads();
        s[t] += x;
        __syncthreads();
    }
    if (i < NN) indptr[i] = csum2[blockIdx.x] + s[t] - v;
    if (i == 0) indptr[NN] = NE;
}

__global__ void k_scatter(const int* __restrict__ row, const int* __restrict__ col,
                          const float* __restrict__ dinv, const int* __restrict__ indptr,
                          int* __restrict__ fill, int* __restrict__ esrc,
                          float* __restrict__ ew) {
    int e = blockIdx.x * 256 + threadIdx.x;
    if (e >= NE) return;
    int r = row[e], c = col[e];
    int pos = indptr[c] + atomicAdd(&fill[c], 1);
    esrc[pos] = r;
    ew[pos] = dinv[r] * dinv[c];
}

// ---------------- W zero-pad: Wp[Kpad x 100], rows >= K are 0 ----------------
__global__ void k_padW(const float* __restrict__ W, float* __restrict__ Wp,
                       int K, int Kpad) {
    int i = blockIdx.x * 256 + threadIdx.x;
    if (i < Kpad * 100) {
        int k = i / 100, c = i - k * 100;
        Wp[i] = (k < K) ? W[k * 100 + c] : 0.f;
    }
}

// ---------------- fp32 GEMM v2: out[M x 100] = A[M x K] @ Wp[Kpad x 100] ------
// lane = row (64 rows/block), wave = 25-col slab. W reads are wave-uniform ->
// scalar loads (SGPR operand to v_fma). A staged transposed in LDS:
// As[kk][row] stride 65 (write conflict-free, read 2-way broadcast = free).
// Per kk per wave: 1 ds_read_b32 + 25 v_fma -> VALU-bound.
__global__ __launch_bounds__(256) void k_gemm2(const float* __restrict__ A,
                                               const float* __restrict__ Wp,
                                               float* __restrict__ out,
                                               int M, int K, int Kpad) {
    __shared__ float smem[6464];            // As (2080) and Cs (6464) overlaid
#define AS(kk, r) smem[(kk) * 65 + (r)]
#define CS(r, c)  smem[(r) * 101 + (c)]
    int t = threadIdx.x;
    int lane = t & 63;
    int wv = __builtin_amdgcn_readfirstlane(t >> 6);  // force wave-uniform
    int rowbase = blockIdx.x * 64;

    float acc[25];
#pragma unroll
    for (int c = 0; c < 25; c++) acc[c] = 0.f;

    for (int k0 = 0; k0 < Kpad; k0 += 32) {
        __syncthreads();
        // stage A[rowbase..+63][k0..+31] -> As[kk][r] (zero-fill outside)
#pragma unroll
        for (int i = 0; i < 8; i++) {
            int e = t + i * 256;            // 0..2047
            int r = e >> 5, kk = e & 31;
            int gr = rowbase + r, gk = k0 + kk;
            AS(kk, r) = (gr < M && gk < K) ? A[(size_t)gr * K + gk] : 0.f;
        }
        __syncthreads();
        const float* wb = Wp + (size_t)k0 * 100 + wv * 25;  // uniform address
#pragma unroll 8
        for (int kk = 0; kk < 32; kk++) {
            float a = AS(kk, lane);
#pragma unroll
            for (int c = 0; c < 25; c++) acc[c] += a * wb[kk * 100 + c];
        }
    }

    // epilogue: transpose through LDS for coalesced stores
    __syncthreads();
#pragma unroll
    for (int c = 0; c < 25; c++) CS(lane, wv * 25 + c) = acc[c];
    __syncthreads();
    int rows = min(64, M - rowbase);
    int total = rows * 100;
    float* ob = out + (size_t)rowbase * 100;
    for (int i = t; i < total; i += 256) {
        int r = i / 100;
        int c = i - r * 100;
        ob[i] = CS(r, c);
    }
#undef AS
#undef CS
}

// ------- aggregation: h[n] = relu(sum_e w*xw[src] + 2*dinv^2*xw[n] + b) -------
// one wave per node; lanes 0..49 each own a float2 (2 cols)
__global__ __launch_bounds__(256) void k_agg(const float* __restrict__ xw,
                                             const int* __restrict__ indptr,
                                             const int* __restrict__ esrc,
                                             const float* __restrict__ ew,
                                             const float* __restrict__ dinv,
                                             const float* __restrict__ bias,
                                             float* __restrict__ hout) {
    int wave = threadIdx.x >> 6;
    int lane = threadIdx.x & 63;
    int n = blockIdx.x * 4 + wave;
    if (n >= NN) return;
    if (lane >= 50) return;
    int beg = indptr[n], end = indptr[n + 1];
    float ax = 0.f, ay = 0.f;
    for (int e = beg; e < end; e++) {
        int s = esrc[e];
        float w = ew[e];
        float2 v = *(const float2*)(xw + (size_t)s * 100 + lane * 2);
        ax += w * v.x;
        ay += w * v.y;
    }
    float di = dinv[n];
    float sw = 2.f * di * di;
    float2 xv = *(const float2*)(xw + (size_t)n * 100 + lane * 2);
    float2 bv = *(const float2*)(bias + lane * 2);
    float2 r;
    r.x = fmaxf(ax + sw * xv.x + bv.x, 0.f);
    r.y = fmaxf(ay + sw * xv.y + bv.y, 0.f);
    *(float2*)(hout + (size_t)n * 100 + lane * 2) = r;
}

// ---------------- pooling ----------------
__global__ void k_gcount(const int* __restrict__ batch, int* __restrict__ gcnt) {
    int n = blockIdx.x * 256 + threadIdx.x;
    if (n < NN) atomicAdd(&gcnt[batch[n]], 1);
}

__global__ void k_gscan(const int* __restrict__ gcnt, int* __restrict__ gstart) {
    __shared__ int s[1024];
    int t = threadIdx.x;
    int v = (t < NG) ? gcnt[t] : 0;
    s[t] = v; __syncthreads();
    for (int o = 1; o < 1024; o <<= 1) {
        int x = (t >= o) ? s[t - o] : 0;
        __syncthreads();
        s[t] += x;
        __syncthreads();
    }
    if (t < NG) gstart[t] = s[t] - v;
}

__global__ void k_pool(const float* __restrict__ h, const int* __restrict__ gcnt,
                       const int* __restrict__ gstart, float* __restrict__ pooled) {
    int g = blockIdx.x, t = threadIdx.x;
    if (t >= 100) return;
    int cnt = gcnt[g], st = gstart[g];
    float s = 0.f;
    for (int i = 0; i < cnt; i++) s += h[(size_t)(st + i) * 100 + t];
    pooled[g * 100 + t] = s / (float)(cnt > 0 ? cnt : 1);
}

// ---------------- MLP head (fused 3 layers, one block per graph) ----------------
__global__ void k_mlp(const float* __restrict__ pooled,
                      const float* __restrict__ Wl1, const float* __restrict__ bl1,
                      const float* __restrict__ Wl2, const float* __restrict__ bl2,
                      const float* __restrict__ Wl3, const float* __restrict__ bl3,
                      float* __restrict__ out) {
    __shared__ float p[100], q[100];
    int g = blockIdx.x, t = threadIdx.x;
    if (t < 100) p[t] = pooled[g * 100 + t];
    __syncthreads();
    float s1 = 0.f;
    if (t < 100) {
        s1 = bl1[t];
        for (int k = 0; k < 100; k++) s1 += p[k] * Wl1[k * 100 + t];
        s1 = fmaxf(s1, 0.f);
    }
    __syncthreads();
    if (t < 100) q[t] = s1;
    __syncthreads();
    float s2 = 0.f;
    if (t < 100) {
        s2 = bl2[t];
        for (int k = 0; k < 100; k++) s2 += q[k] * Wl2[k * 100 + t];
        s2 = fmaxf(s2, 0.f);
    }
    __syncthreads();
    if (t < 100) p[t] = s2;
    __syncthreads();
    if (t < 29) {
        float s3 = bl3[t];
        for (int k = 0; k < 100; k++) s3 += p[k] * Wl3[k * 29 + t];
        out[g * 29 + t] = s3;
    }
}

// ---------------- launch ----------------
extern "C" void kernel_launch(void* const* d_in, const int* in_sizes, int n_in,
                              void* d_out, int out_size, void* d_ws, size_t ws_size,
                              hipStream_t stream) {
    const float* x     = (const float*)d_in[0];
    const int*   ei    = (const int*)d_in[1];
    const int*   batch = (const int*)d_in[2];
    const float* W1 = (const float*)d_in[3];  const float* b1 = (const float*)d_in[4];
    const float* W2 = (const float*)d_in[5];  const float* b2 = (const float*)d_in[6];
    const float* W3 = (const float*)d_in[7];  const float* b3 = (const float*)d_in[8];
    const float* W4 = (const float*)d_in[9];  const float* b4 = (const float*)d_in[10];
    const float* W5 = (const float*)d_in[11]; const float* b5 = (const float*)d_in[12];
    const float* Wl1 = (const float*)d_in[13]; const float* bl1 = (const float*)d_in[14];
    const float* Wl2 = (const float*)d_in[15]; const float* bl2 = (const float*)d_in[16];
    const float* Wl3 = (const float*)d_in[17]; const float* bl3 = (const float*)d_in[18];
    float* out = (float*)d_out;

    const int* row = ei;
    const int* col = ei + NE;

    // workspace carve-up (256B aligned)
    uintptr_t base = (uintptr_t)d_ws;
    auto alloc = [&](size_t bytes) -> void* {
        void* p = (void*)base;
        base += (bytes + 255) & ~(size_t)255;
        return p;
    };
    int*   degcnt = (int*)alloc(NN * 4);
    float* dinv   = (float*)alloc(NN * 4);
    int*   indptr = (int*)alloc((NN + 1) * 4);
    int*   fill   = (int*)alloc(NN * 4);
    int*   csum   = (int*)alloc(512 * 4);
    int*   csum2  = (int*)alloc(512 * 4);
    int*   gcnt   = (int*)alloc(1024 * 4);
    int*   gstart = (int*)alloc(1024 * 4);
    int*   esrc   = (int*)alloc((size_t)NE * 4);
    float* ew     = (float*)alloc((size_t)NE * 4);
    float* xw     = (float*)alloc((size_t)NN * 100 * 4);
    float* h      = (float*)alloc((size_t)NN * 100 * 4);
    float* pooled = (float*)alloc((size_t)NG * 100 * 4);
    float* wp1    = (float*)alloc((size_t)352 * 100 * 4);
    float* wp2    = (float*)alloc((size_t)128 * 100 * 4);
    float* wp3    = (float*)alloc((size_t)128 * 100 * 4);
    float* wp4    = (float*)alloc((size_t)128 * 100 * 4);
    float* wp5    = (float*)alloc((size_t)128 * 100 * 4);

    // zero the atomic counters (ws is poisoned 0xAA before every call)
    hipMemsetAsync(degcnt, 0, NN * 4, stream);
    hipMemsetAsync(fill, 0, NN * 4, stream);
    hipMemsetAsync(gcnt, 0, 1024 * 4, stream);

    const int NB = (NN + 255) / 256;  // 391
    k_deg<<<(NE + 255) / 256, 256, 0, stream>>>(col, degcnt);
    k_dinv<<<NB, 256, 0, stream>>>(degcnt, dinv);
    k_scan1<<<NB, 256, 0, stream>>>(degcnt, csum);
    k_scan2<<<1, 512, 0, stream>>>(csum, csum2, NB);
    k_scan3<<<NB, 256, 0, stream>>>(degcnt, csum2, indptr);
    k_scatter<<<(NE + 255) / 256, 256, 0, stream>>>(row, col, dinv, indptr, fill, esrc, ew);

    k_padW<<<(352 * 100 + 255) / 256, 256, 0, stream>>>(W1, wp1, 336, 352);
    k_padW<<<(128 * 100 + 255) / 256, 256, 0, stream>>>(W2, wp2, 100, 128);
    k_padW<<<(128 * 100 + 255) / 256, 256, 0, stream>>>(W3, wp3, 100, 128);
    k_padW<<<(128 * 100 + 255) / 256, 256, 0, stream>>>(W4, wp4, 100, 128);
    k_padW<<<(128 * 100 + 255) / 256, 256, 0, stream>>>(W5, wp5, 100, 128);

    const int GEMM_GRID = (NN + 63) / 64;  // 1563
    const int AGG_GRID = (NN + 3) / 4;     // 25000

    k_gemm2<<<GEMM_GRID, 256, 0, stream>>>(x, wp1, xw, NN, 336, 352);
    k_agg<<<AGG_GRID, 256, 0, stream>>>(xw, indptr, esrc, ew, dinv, b1, h);
    k_gemm2<<<GEMM_GRID, 256, 0, stream>>>(h, wp2, xw, NN, 100, 128);
    k_agg<<<AGG_GRID, 256, 0, stream>>>(xw, indptr, esrc, ew, dinv, b2, h);
    k_gemm2<<<GEMM_GRID, 256, 0, stream>>>(h, wp3, xw, NN, 100, 128);
    k_agg<<<AGG_GRID, 256, 0, stream>>>(xw, indptr, esrc, ew, dinv, b3, h);
    k_gemm2<<<GEMM_GRID, 256, 0, stream>>>(h, wp4, xw, NN, 100, 128);
    k_agg<<<AGG_GRID, 256, 0, stream>>>(xw, indptr, esrc, ew, dinv, b4, h);
    k_gemm2<<<GEMM_GRID, 256, 0, stream>>>(h, wp5, xw, NN, 100, 128);
    k_agg<<<AGG_GRID, 256, 0, stream>>>(xw, indptr, esrc, ew, dinv, b5, h);

    k_gcount<<<NB, 256, 0, stream>>>(batch, gcnt);
    k_gscan<<<1, 1024, 0, stream>>>(gcnt, gstart);
    k_pool<<<NG, 128, 0, stream>>>(h, gcnt, gstart, pooled);
    k_mlp<<<NG, 128, 0, stream>>>(pooled, Wl1, bl1, Wl2, bl2, Wl3, bl3, out);
}

// Round 3
// 1499.492 us; speedup vs baseline: 1.5163x; 1.1314x over previous
//
#include <hip/hip_runtime.h>
#include <stdint.h>

#define NN 100000
#define NE 1600000
#define NG 1000

typedef float f32x4 __attribute__((ext_vector_type(4)));
typedef short s16x8 __attribute__((ext_vector_type(8)));

__device__ __forceinline__ unsigned short f2bf(float f) {
    unsigned u = __builtin_bit_cast(unsigned, f);
    unsigned r = u + 0x7FFFu + ((u >> 16) & 1u);
    return (unsigned short)(r >> 16);
}
__device__ __forceinline__ float bf2f(unsigned short h) {
    unsigned u = ((unsigned)h) << 16;
    return __builtin_bit_cast(float, u);
}

// ---------------- degree / dinv ----------------
__global__ void k_deg(const int* __restrict__ col, int* __restrict__ cnt) {
    int e = blockIdx.x * 256 + threadIdx.x;
    if (e < NE) atomicAdd(&cnt[col[e]], 1);
}

__global__ void k_dinv(const int* __restrict__ cnt, float* __restrict__ dinv) {
    int n = blockIdx.x * 256 + threadIdx.x;
    if (n < NN) dinv[n] = 1.0f / sqrtf((float)cnt[n] + 2.0f);
}

// ---------------- prefix scans for CSR ----------------
__global__ void k_scan1(const int* __restrict__ cnt, int* __restrict__ csum) {
    __shared__ int s[256];
    int i = blockIdx.x * 256 + threadIdx.x;
    s[threadIdx.x] = (i < NN) ? cnt[i] : 0;
    __syncthreads();
    for (int o = 128; o > 0; o >>= 1) {
        if (threadIdx.x < o) s[threadIdx.x] += s[threadIdx.x + o];
        __syncthreads();
    }
    if (threadIdx.x == 0) csum[blockIdx.x] = s[0];
}

__global__ void k_scan2(const int* __restrict__ csum, int* __restrict__ csum2, int nb) {
    __shared__ int s[512];
    int t = threadIdx.x;
    int v = (t < nb) ? csum[t] : 0;
    s[t] = v; __syncthreads();
    for (int o = 1; o < 512; o <<= 1) {
        int x = (t >= o) ? s[t - o] : 0;
        __syncthreads();
        s[t] += x;
        __syncthreads();
    }
    if (t < nb) csum2[t] = s[t] - v;  // exclusive
}

__global__ void k_scan3(const int* __restrict__ cnt, const int* __restrict__ csum2,
                        int* __restrict__ indptr) {
    __shared__ int s[256];
    int t = threadIdx.x;
    int i = blockIdx.x * 256 + t;
    int v = (i < NN) ? cnt[i] : 0;
    s[t] = v; __syncthreads();
    for (int o = 1; o < 256; o <<= 1) {
        int x = (t >= o) ? s[t - o] : 0;
        __syncthreads();
        s[t] += x;
        __syncthreads();
    }
    if (i < NN) indptr[i] = csum2[blockIdx.x] + s[t] - v;
    if (i == 0) indptr[NN] = NE;
}

__global__ void k_scatter(const int* __restrict__ row, const int* __restrict__ col,
                          const float* __restrict__ dinv, const int* __restrict__ indptr,
                          int* __restrict__ fill, int* __restrict__ esrc,
                          float* __restrict__ ew) {
    int e = blockIdx.x * 256 + threadIdx.x;
    if (e >= NE) return;
    int r = row[e], c = col[e];
    int pos = indptr[c] + atomicAdd(&fill[c], 1);
    esrc[pos] = r;
    ew[pos] = dinv[r] * dinv[c];
}

// ----- W split+transpose: Wt_{hi,lo}[112][KCP] bf16, zero-padded -----
__global__ void k_convW(const float* __restrict__ W,
                        unsigned short* __restrict__ Whi,
                        unsigned short* __restrict__ Wlo, int K, int KCP) {
    int idx = blockIdx.x * 256 + threadIdx.x;
    if (idx >= 112 * KCP) return;
    int n = idx / KCP, k = idx - n * KCP;
    float v = (n < 100 && k < K) ? W[k * 100 + n] : 0.f;
    unsigned short hi = f2bf(v);
    float r = v - bf2f(hi);
    Whi[idx] = hi;
    Wlo[idx] = f2bf(r);
}

// ---- split-bf16 MFMA GEMM: out[M x 100] = A[M x K] @ W[K x 100] (fp32-class) ----
// block: 256 thr = 4 waves; block tile 64 rows x 112 cols; wave = 16 rows.
// K chunks of 64 staged in LDS (A fp32; W as hi/lo bf16, transposed [n][k]).
// Per (tile, K-step): 3 MFMAs: Ahi*Whi + Ahi*Wlo + Alo*Whi  (err ~2^-17 rel).
// Fragment layouts (m89/m120 verified): A: m=lane&15, k=quad*8+j;
// B: n=lane&15, k=quad*8+j; C/D: n=lane&15, m=quad*4+reg.
__global__ __launch_bounds__(256) void k_gemm3(const float* __restrict__ A,
                                               const unsigned short* __restrict__ Wthi,
                                               const unsigned short* __restrict__ Wtlo,
                                               float* __restrict__ out,
                                               int M, int K, int KCP) {
    __shared__ float As[64 * 68];             // stride 68 dw: uniform bank starts
    __shared__ unsigned short Hs[112 * 72];   // stride 72 sh = 36 dw: uniform starts
    __shared__ unsigned short Ls[112 * 72];
    int t = threadIdx.x;
    int lane = t & 63;
    int wv = t >> 6;
    int l15 = lane & 15, quad = lane >> 4;
    int rowbase = blockIdx.x * 64;

    f32x4 acc[7];
#pragma unroll
    for (int i = 0; i < 7; i++)
#pragma unroll
        for (int r = 0; r < 4; r++) acc[i][r] = 0.f;

    for (int k0 = 0; k0 < KCP; k0 += 64) {
        __syncthreads();
        // stage A: 64 rows x 64 k, float4 loads (K%4==0 so guard is per-float4)
#pragma unroll
        for (int j = 0; j < 4; j++) {
            int e = t + j * 256;            // 0..1023
            int r = e >> 4;                 // 16 float4 per row
            int c4 = (e & 15) * 4;
            int gr = rowbase + r, gk = k0 + c4;
            float4 v = make_float4(0.f, 0.f, 0.f, 0.f);
            if (gr < M && gk < K) v = *(const float4*)(A + (size_t)gr * K + gk);
            *(float4*)(&As[r * 68 + c4]) = v;
        }
        // stage W chunk: 112 n x 64 k shorts, hi+lo, uint2 (4 shorts) loads
#pragma unroll
        for (int j = 0; j < 7; j++) {
            int e = t + j * 256;            // 0..1791
            int n = e >> 4;                 // 16 uint2 per row
            int c = (e & 15) * 4;
            size_t g = (size_t)n * KCP + k0 + c;
            *(uint2*)(&Hs[n * 72 + c]) = *(const uint2*)(Wthi + g);
            *(uint2*)(&Ls[n * 72 + c]) = *(const uint2*)(Wtlo + g);
        }
        __syncthreads();
#pragma unroll
        for (int ks = 0; ks < 2; ks++) {
            // build A fragments (hi/lo) from fp32 LDS tile
            int arow = wv * 16 + l15;
            const float* ap = &As[arow * 68 + ks * 32 + quad * 8];
            float4 a0 = *(const float4*)ap;
            float4 a1 = *(const float4*)(ap + 4);
            float af[8] = {a0.x, a0.y, a0.z, a0.w, a1.x, a1.y, a1.z, a1.w};
            s16x8 ahi, alo;
#pragma unroll
            for (int j = 0; j < 8; j++) {
                unsigned short h = f2bf(af[j]);
                ahi[j] = (short)h;
                alo[j] = (short)f2bf(af[j] - bf2f(h));
            }
            int koff = ks * 32 + quad * 8;
#pragma unroll
            for (int tt = 0; tt < 7; tt++) {
                int nrow = tt * 16 + l15;
                s16x8 bhi = *(const s16x8*)(&Hs[nrow * 72 + koff]);
                s16x8 blo = *(const s16x8*)(&Ls[nrow * 72 + koff]);
                acc[tt] = __builtin_amdgcn_mfma_f32_16x16x32_bf16(ahi, bhi, acc[tt], 0, 0, 0);
                acc[tt] = __builtin_amdgcn_mfma_f32_16x16x32_bf16(ahi, blo, acc[tt], 0, 0, 0);
                acc[tt] = __builtin_amdgcn_mfma_f32_16x16x32_bf16(alo, bhi, acc[tt], 0, 0, 0);
            }
        }
    }

    // store: lane holds rows quad*4+reg (within wave's 16), col l15 per tile
    int gr0 = rowbase + wv * 16 + quad * 4;
#pragma unroll
    for (int tt = 0; tt < 7; tt++) {
        int n = tt * 16 + l15;
        if (n >= 100) continue;
#pragma unroll
        for (int reg = 0; reg < 4; reg++) {
            int gr = gr0 + reg;
            if (gr < M) out[(size_t)gr * 100 + n] = acc[tt][reg];
        }
    }
}

// ------- aggregation: h[n] = relu(sum_e w*xw[src] + 2*dinv^2*xw[n] + b) -------
__global__ __launch_bounds__(256) void k_agg(const float* __restrict__ xw,
                                             const int* __restrict__ indptr,
                                             const int* __restrict__ esrc,
                                             const float* __restrict__ ew,
                                             const float* __restrict__ dinv,
                                             const float* __restrict__ bias,
                                             float* __restrict__ hout) {
    int wave = threadIdx.x >> 6;
    int lane = threadIdx.x & 63;
    int n = blockIdx.x * 4 + wave;
    if (n >= NN) return;
    if (lane >= 50) return;
    int beg = indptr[n], end = indptr[n + 1];
    float ax = 0.f, ay = 0.f;
    for (int e = beg; e < end; e++) {
        int s = esrc[e];
        float w = ew[e];
        float2 v = *(const float2*)(xw + (size_t)s * 100 + lane * 2);
        ax += w * v.x;
        ay += w * v.y;
    }
    float di = dinv[n];
    float sw = 2.f * di * di;
    float2 xv = *(const float2*)(xw + (size_t)n * 100 + lane * 2);
    float2 bv = *(const float2*)(bias + lane * 2);
    float2 r;
    r.x = fmaxf(ax + sw * xv.x + bv.x, 0.f);
    r.y = fmaxf(ay + sw * xv.y + bv.y, 0.f);
    *(float2*)(hout + (size_t)n * 100 + lane * 2) = r;
}

// ---------------- pooling ----------------
__global__ void k_gcount(const int* __restrict__ batch, int* __restrict__ gcnt) {
    int n = blockIdx.x * 256 + threadIdx.x;
    if (n < NN) atomicAdd(&gcnt[batch[n]], 1);
}

__global__ void k_gscan(const int* __restrict__ gcnt, int* __restrict__ gstart) {
    __shared__ int s[1024];
    int t = threadIdx.x;
    int v = (t < NG) ? gcnt[t] : 0;
    s[t] = v; __syncthreads();
    for (int o = 1; o < 1024; o <<= 1) {
        int x = (t >= o) ? s[t - o] : 0;
        __syncthreads();
        s[t] += x;
        __syncthreads();
    }
    if (t < NG) gstart[t] = s[t] - v;
}

__global__ void k_pool(const float* __restrict__ h, const int* __restrict__ gcnt,
                       const int* __restrict__ gstart, float* __restrict__ pooled) {
    int g = blockIdx.x, t = threadIdx.x;
    if (t >= 100) return;
    int cnt = gcnt[g], st = gstart[g];
    float s = 0.f;
    for (int i = 0; i < cnt; i++) s += h[(size_t)(st + i) * 100 + t];
    pooled[g * 100 + t] = s / (float)(cnt > 0 ? cnt : 1);
}

// ---------------- MLP head (fused 3 layers, one block per graph) ----------------
__global__ void k_mlp(const float* __restrict__ pooled,
                      const float* __restrict__ Wl1, const float* __restrict__ bl1,
                      const float* __restrict__ Wl2, const float* __restrict__ bl2,
                      const float* __restrict__ Wl3, const float* __restrict__ bl3,
                      float* __restrict__ out) {
    __shared__ float p[100], q[100];
    int g = blockIdx.x, t = threadIdx.x;
    if (t < 100) p[t] = pooled[g * 100 + t];
    __syncthreads();
    float s1 = 0.f;
    if (t < 100) {
        s1 = bl1[t];
        for (int k = 0; k < 100; k++) s1 += p[k] * Wl1[k * 100 + t];
        s1 = fmaxf(s1, 0.f);
    }
    __syncthreads();
    if (t < 100) q[t] = s1;
    __syncthreads();
    float s2 = 0.f;
    if (t < 100) {
        s2 = bl2[t];
        for (int k = 0; k < 100; k++) s2 += q[k] * Wl2[k * 100 + t];
        s2 = fmaxf(s2, 0.f);
    }
    __syncthreads();
    if (t < 100) p[t] = s2;
    __syncthreads();
    if (t < 29) {
        float s3 = bl3[t];
        for (int k = 0; k < 100; k++) s3 += p[k] * Wl3[k * 29 + t];
        out[g * 29 + t] = s3;
    }
}

// ---------------- launch ----------------
extern "C" void kernel_launch(void* const* d_in, const int* in_sizes, int n_in,
                              void* d_out, int out_size, void* d_ws, size_t ws_size,
                              hipStream_t stream) {
    const float* x     = (const float*)d_in[0];
    const int*   ei    = (const int*)d_in[1];
    const int*   batch = (const int*)d_in[2];
    const float* W1 = (const float*)d_in[3];  const float* b1 = (const float*)d_in[4];
    const float* W2 = (const float*)d_in[5];  const float* b2 = (const float*)d_in[6];
    const float* W3 = (const float*)d_in[7];  const float* b3 = (const float*)d_in[8];
    const float* W4 = (const float*)d_in[9];  const float* b4 = (const float*)d_in[10];
    const float* W5 = (const float*)d_in[11]; const float* b5 = (const float*)d_in[12];
    const float* Wl1 = (const float*)d_in[13]; const float* bl1 = (const float*)d_in[14];
    const float* Wl2 = (const float*)d_in[15]; const float* bl2 = (const float*)d_in[16];
    const float* Wl3 = (const float*)d_in[17]; const float* bl3 = (const float*)d_in[18];
    float* out = (float*)d_out;

    const int* row = ei;
    const int* col = ei + NE;

    // workspace carve-up (256B aligned)
    uintptr_t base = (uintptr_t)d_ws;
    auto alloc = [&](size_t bytes) -> void* {
        void* p = (void*)base;
        base += (bytes + 255) & ~(size_t)255;
        return p;
    };
    int*   degcnt = (int*)alloc(NN * 4);
    float* dinv   = (float*)alloc(NN * 4);
    int*   indptr = (int*)alloc((NN + 1) * 4);
    int*   fill   = (int*)alloc(NN * 4);
    int*   csum   = (int*)alloc(512 * 4);
    int*   csum2  = (int*)alloc(512 * 4);
    int*   gcnt   = (int*)alloc(1024 * 4);
    int*   gstart = (int*)alloc(1024 * 4);
    int*   esrc   = (int*)alloc((size_t)NE * 4);
    float* ew     = (float*)alloc((size_t)NE * 4);
    float* xw     = (float*)alloc((size_t)NN * 100 * 4);
    float* h      = (float*)alloc((size_t)NN * 100 * 4);
    float* pooled = (float*)alloc((size_t)NG * 100 * 4);
    unsigned short* w1hi = (unsigned short*)alloc((size_t)112 * 384 * 2);
    unsigned short* w1lo = (unsigned short*)alloc((size_t)112 * 384 * 2);
    unsigned short* w2hi = (unsigned short*)alloc((size_t)112 * 128 * 2);
    unsigned short* w2lo = (unsigned short*)alloc((size_t)112 * 128 * 2);
    unsigned short* w3hi = (unsigned short*)alloc((size_t)112 * 128 * 2);
    unsigned short* w3lo = (unsigned short*)alloc((size_t)112 * 128 * 2);
    unsigned short* w4hi = (unsigned short*)alloc((size_t)112 * 128 * 2);
    unsigned short* w4lo = (unsigned short*)alloc((size_t)112 * 128 * 2);
    unsigned short* w5hi = (unsigned short*)alloc((size_t)112 * 128 * 2);
    unsigned short* w5lo = (unsigned short*)alloc((size_t)112 * 128 * 2);

    // zero the atomic counters (ws is poisoned 0xAA before every call)
    hipMemsetAsync(degcnt, 0, NN * 4, stream);
    hipMemsetAsync(fill, 0, NN * 4, stream);
    hipMemsetAsync(gcnt, 0, 1024 * 4, stream);

    const int NB = (NN + 255) / 256;  // 391
    k_deg<<<(NE + 255) / 256, 256, 0, stream>>>(col, degcnt);
    k_dinv<<<NB, 256, 0, stream>>>(degcnt, dinv);
    k_scan1<<<NB, 256, 0, stream>>>(degcnt, csum);
    k_scan2<<<1, 512, 0, stream>>>(csum, csum2, NB);
    k_scan3<<<NB, 256, 0, stream>>>(degcnt, csum2, indptr);
    k_scatter<<<(NE + 255) / 256, 256, 0, stream>>>(row, col, dinv, indptr, fill, esrc, ew);

    k_convW<<<(112 * 384 + 255) / 256, 256, 0, stream>>>(W1, w1hi, w1lo, 336, 384);
    k_convW<<<(112 * 128 + 255) / 256, 256, 0, stream>>>(W2, w2hi, w2lo, 100, 128);
    k_convW<<<(112 * 128 + 255) / 256, 256, 0, stream>>>(W3, w3hi, w3lo, 100, 128);
    k_convW<<<(112 * 128 + 255) / 256, 256, 0, stream>>>(W4, w4hi, w4lo, 100, 128);
    k_convW<<<(112 * 128 + 255) / 256, 256, 0, stream>>>(W5, w5hi, w5lo, 100, 128);

    const int GEMM_GRID = (NN + 63) / 64;  // 1563
    const int AGG_GRID = (NN + 3) / 4;     // 25000

    k_gemm3<<<GEMM_GRID, 256, 0, stream>>>(x, w1hi, w1lo, xw, NN, 336, 384);
    k_agg<<<AGG_GRID, 256, 0, stream>>>(xw, indptr, esrc, ew, dinv, b1, h);
    k_gemm3<<<GEMM_GRID, 256, 0, stream>>>(h, w2hi, w2lo, xw, NN, 100, 128);
    k_agg<<<AGG_GRID, 256, 0, stream>>>(xw, indptr, esrc, ew, dinv, b2, h);
    k_gemm3<<<GEMM_GRID, 256, 0, stream>>>(h, w3hi, w3lo, xw, NN, 100, 128);
    k_agg<<<AGG_GRID, 256, 0, stream>>>(xw, indptr, esrc, ew, dinv, b3, h);
    k_gemm3<<<GEMM_GRID, 256, 0, stream>>>(h, w4hi, w4lo, xw, NN, 100, 128);
    k_agg<<<AGG_GRID, 256, 0, stream>>>(xw, indptr, esrc, ew, dinv, b4, h);
    k_gemm3<<<GEMM_GRID, 256, 0, stream>>>(h, w5hi, w5lo, xw, NN, 100, 128);
    k_agg<<<AGG_GRID, 256, 0, stream>>>(xw, indptr, esrc, ew, dinv, b5, h);

    k_gcount<<<NB, 256, 0, stream>>>(batch, gcnt);
    k_gscan<<<1, 1024, 0, stream>>>(gcnt, gstart);
    k_pool<<<NG, 128, 0, stream>>>(h, gcnt, gstart, pooled);
    k_mlp<<<NG, 128, 0, stream>>>(pooled, Wl1, bl1, Wl2, bl2, Wl3, bl3, out);
}

// Round 4
// 1236.974 us; speedup vs baseline: 1.8381x; 1.2122x over previous
//
#include <hip/hip_runtime.h>
#include <stdint.h>

#define NN 100000
#define NE 1600000
#define NG 1000
#define LDA 112   // padded row stride (floats) for xw/h: 448 B, 64B-aligned rows

typedef float f32x4 __attribute__((ext_vector_type(4)));
typedef short s16x8 __attribute__((ext_vector_type(8)));

__device__ __forceinline__ unsigned short f2bf(float f) {
    unsigned u = __builtin_bit_cast(unsigned, f);
    unsigned r = u + 0x7FFFu + ((u >> 16) & 1u);
    return (unsigned short)(r >> 16);
}
__device__ __forceinline__ float bf2f(unsigned short h) {
    unsigned u = ((unsigned)h) << 16;
    return __builtin_bit_cast(float, u);
}
__device__ __forceinline__ float readlane_f(float v, int l) {
    return __builtin_bit_cast(float, __builtin_amdgcn_readlane(__builtin_bit_cast(int, v), l));
}

// ---------------- degree / dinv ----------------
__global__ void k_deg(const int* __restrict__ col, int* __restrict__ cnt) {
    int e = blockIdx.x * 256 + threadIdx.x;
    if (e < NE) atomicAdd(&cnt[col[e]], 1);
}

__global__ void k_dinv(const int* __restrict__ cnt, float* __restrict__ dinv) {
    int n = blockIdx.x * 256 + threadIdx.x;
    if (n < NN) dinv[n] = 1.0f / sqrtf((float)cnt[n] + 2.0f);
}

// ---------------- prefix scans for CSR ----------------
__global__ void k_scan1(const int* __restrict__ cnt, int* __restrict__ csum) {
    __shared__ int s[256];
    int i = blockIdx.x * 256 + threadIdx.x;
    s[threadIdx.x] = (i < NN) ? cnt[i] : 0;
    __syncthreads();
    for (int o = 128; o > 0; o >>= 1) {
        if (threadIdx.x < o) s[threadIdx.x] += s[threadIdx.x + o];
        __syncthreads();
    }
    if (threadIdx.x == 0) csum[blockIdx.x] = s[0];
}

__global__ void k_scan2(const int* __restrict__ csum, int* __restrict__ csum2, int nb) {
    __shared__ int s[512];
    int t = threadIdx.x;
    int v = (t < nb) ? csum[t] : 0;
    s[t] = v; __syncthreads();
    for (int o = 1; o < 512; o <<= 1) {
        int x = (t >= o) ? s[t - o] : 0;
        __syncthreads();
        s[t] += x;
        __syncthreads();
    }
    if (t < nb) csum2[t] = s[t] - v;  // exclusive
}

__global__ void k_scan3(const int* __restrict__ cnt, const int* __restrict__ csum2,
                        int* __restrict__ indptr) {
    __shared__ int s[256];
    int t = threadIdx.x;
    int i = blockIdx.x * 256 + t;
    int v = (i < NN) ? cnt[i] : 0;
    s[t] = v; __syncthreads();
    for (int o = 1; o < 256; o <<= 1) {
        int x = (t >= o) ? s[t - o] : 0;
        __syncthreads();
        s[t] += x;
        __syncthreads();
    }
    if (i < NN) indptr[i] = csum2[blockIdx.x] + s[t] - v;
    if (i == 0) indptr[NN] = NE;
}

__global__ void k_scatter(const int* __restrict__ row, const int* __restrict__ col,
                          const float* __restrict__ dinv, const int* __restrict__ indptr,
                          int* __restrict__ fill, int* __restrict__ esrc,
                          float* __restrict__ ew) {
    int e = blockIdx.x * 256 + threadIdx.x;
    if (e >= NE) return;
    int r = row[e], c = col[e];
    int pos = indptr[c] + atomicAdd(&fill[c], 1);
    esrc[pos] = r;
    ew[pos] = dinv[r] * dinv[c];
}

// ----- W split+transpose: Wt_{hi,lo}[112][KCP] bf16, zero-padded -----
__global__ void k_convW(const float* __restrict__ W,
                        unsigned short* __restrict__ Whi,
                        unsigned short* __restrict__ Wlo, int K, int KCP) {
    int idx = blockIdx.x * 256 + threadIdx.x;
    if (idx >= 112 * KCP) return;
    int n = idx / KCP, k = idx - n * KCP;
    float v = (n < 100 && k < K) ? W[k * 100 + n] : 0.f;
    unsigned short hi = f2bf(v);
    float r = v - bf2f(hi);
    Whi[idx] = hi;
    Wlo[idx] = f2bf(r);
}

// ---- split-bf16 MFMA GEMM: out[M x 112(LDA)] = A[M x K, stride lda] @ W ----
__global__ __launch_bounds__(256) void k_gemm3(const float* __restrict__ A,
                                               const unsigned short* __restrict__ Wthi,
                                               const unsigned short* __restrict__ Wtlo,
                                               float* __restrict__ out,
                                               int M, int K, int KCP, int lda) {
    __shared__ float As[64 * 68];
    __shared__ unsigned short Hs[112 * 72];
    __shared__ unsigned short Ls[112 * 72];
    int t = threadIdx.x;
    int lane = t & 63;
    int wv = t >> 6;
    int l15 = lane & 15, quad = lane >> 4;
    int rowbase = blockIdx.x * 64;

    f32x4 acc[7];
#pragma unroll
    for (int i = 0; i < 7; i++)
#pragma unroll
        for (int r = 0; r < 4; r++) acc[i][r] = 0.f;

    for (int k0 = 0; k0 < KCP; k0 += 64) {
        __syncthreads();
#pragma unroll
        for (int j = 0; j < 4; j++) {
            int e = t + j * 256;
            int r = e >> 4;
            int c4 = (e & 15) * 4;
            int gr = rowbase + r, gk = k0 + c4;
            float4 v = make_float4(0.f, 0.f, 0.f, 0.f);
            if (gr < M && gk < K) v = *(const float4*)(A + (size_t)gr * lda + gk);
            *(float4*)(&As[r * 68 + c4]) = v;
        }
#pragma unroll
        for (int j = 0; j < 7; j++) {
            int e = t + j * 256;
            int n = e >> 4;
            int c = (e & 15) * 4;
            size_t g = (size_t)n * KCP + k0 + c;
            *(uint2*)(&Hs[n * 72 + c]) = *(const uint2*)(Wthi + g);
            *(uint2*)(&Ls[n * 72 + c]) = *(const uint2*)(Wtlo + g);
        }
        __syncthreads();
#pragma unroll
        for (int ks = 0; ks < 2; ks++) {
            int arow = wv * 16 + l15;
            const float* ap = &As[arow * 68 + ks * 32 + quad * 8];
            float4 a0 = *(const float4*)ap;
            float4 a1 = *(const float4*)(ap + 4);
            float af[8] = {a0.x, a0.y, a0.z, a0.w, a1.x, a1.y, a1.z, a1.w};
            s16x8 ahi, alo;
#pragma unroll
            for (int j = 0; j < 8; j++) {
                unsigned short h = f2bf(af[j]);
                ahi[j] = (short)h;
                alo[j] = (short)f2bf(af[j] - bf2f(h));
            }
            int koff = ks * 32 + quad * 8;
#pragma unroll
            for (int tt = 0; tt < 7; tt++) {
                int nrow = tt * 16 + l15;
                s16x8 bhi = *(const s16x8*)(&Hs[nrow * 72 + koff]);
                s16x8 blo = *(const s16x8*)(&Ls[nrow * 72 + koff]);
                acc[tt] = __builtin_amdgcn_mfma_f32_16x16x32_bf16(ahi, bhi, acc[tt], 0, 0, 0);
                acc[tt] = __builtin_amdgcn_mfma_f32_16x16x32_bf16(ahi, blo, acc[tt], 0, 0, 0);
                acc[tt] = __builtin_amdgcn_mfma_f32_16x16x32_bf16(alo, bhi, acc[tt], 0, 0, 0);
            }
        }
    }

    // store all 112 cols (pad cols are exact zeros from W zero-pad)
    int gr0 = rowbase + wv * 16 + quad * 4;
#pragma unroll
    for (int tt = 0; tt < 7; tt++) {
        int n = tt * 16 + l15;
#pragma unroll
        for (int reg = 0; reg < 4; reg++) {
            int gr = gr0 + reg;
            if (gr < M) out[(size_t)gr * LDA + n] = acc[tt][reg];
        }
    }
}

// ------- aggregation: h[n] = relu(sum_e w*xw[src] + 2*dinv^2*xw[n] + b) -------
// one wave per node; cooperative esrc/ew load + readlane broadcast; 8 gathers
// in flight per wave (MLP). lanes 0..49 own a float2; 50..63 clamp to col 0.
__global__ __launch_bounds__(256) void k_agg(const float* __restrict__ xw,
                                             const int* __restrict__ indptr,
                                             const int* __restrict__ esrc,
                                             const float* __restrict__ ew,
                                             const float* __restrict__ dinv,
                                             const float* __restrict__ bias,
                                             float* __restrict__ hout) {
    int wave = threadIdx.x >> 6;
    int lane = threadIdx.x & 63;
    int n = blockIdx.x * 4 + wave;
    if (n >= NN) return;
    int beg = indptr[n], end = indptr[n + 1];
    int col = (lane < 50) ? lane * 2 : 0;
    float ax = 0.f, ay = 0.f;
    for (int c = beg; c < end; c += 64) {
        int m = min(64, end - c);
        int se = 0; float we = 0.f;
        if (lane < m) { se = esrc[c + lane]; we = ew[c + lane]; }
        int j = 0;
        for (; j + 8 <= m; j += 8) {
            float2 v[8]; float w[8];
#pragma unroll
            for (int u = 0; u < 8; u++) {
                int s = __builtin_amdgcn_readlane(se, j + u);
                w[u] = readlane_f(we, j + u);
                v[u] = *(const float2*)(xw + (size_t)s * LDA + col);
            }
#pragma unroll
            for (int u = 0; u < 8; u++) { ax += w[u] * v[u].x; ay += w[u] * v[u].y; }
        }
        for (; j < m; j++) {
            int s = __builtin_amdgcn_readlane(se, j);
            float w = readlane_f(we, j);
            float2 v = *(const float2*)(xw + (size_t)s * LDA + col);
            ax += w * v.x; ay += w * v.y;
        }
    }
    if (lane < 50) {
        float di = dinv[n];
        float sw = 2.f * di * di;
        float2 xv = *(const float2*)(xw + (size_t)n * LDA + col);
        float2 bv = *(const float2*)(bias + lane * 2);
        float2 r;
        r.x = fmaxf(ax + sw * xv.x + bv.x, 0.f);
        r.y = fmaxf(ay + sw * xv.y + bv.y, 0.f);
        *(float2*)(hout + (size_t)n * LDA + col) = r;
    }
}

// ---------------- pooling ----------------
__global__ void k_gcount(const int* __restrict__ batch, int* __restrict__ gcnt) {
    int n = blockIdx.x * 256 + threadIdx.x;
    if (n < NN) atomicAdd(&gcnt[batch[n]], 1);
}

__global__ void k_gscan(const int* __restrict__ gcnt, int* __restrict__ gstart) {
    __shared__ int s[1024];
    int t = threadIdx.x;
    int v = (t < NG) ? gcnt[t] : 0;
    s[t] = v; __syncthreads();
    for (int o = 1; o < 1024; o <<= 1) {
        int x = (t >= o) ? s[t - o] : 0;
        __syncthreads();
        s[t] += x;
        __syncthreads();
    }
    if (t < NG) gstart[t] = s[t] - v;
}

__global__ void k_pool(const float* __restrict__ h, const int* __restrict__ gcnt,
                       const int* __restrict__ gstart, float* __restrict__ pooled) {
    int g = blockIdx.x, t = threadIdx.x;
    if (t >= 100) return;
    int cnt = gcnt[g], st = gstart[g];
    float s = 0.f;
    for (int i = 0; i < cnt; i++) s += h[(size_t)(st + i) * LDA + t];
    pooled[g * 100 + t] = s / (float)(cnt > 0 ? cnt : 1);
}

// ---------------- MLP head (fused 3 layers, one block per graph) ----------------
__global__ void k_mlp(const float* __restrict__ pooled,
                      const float* __restrict__ Wl1, const float* __restrict__ bl1,
                      const float* __restrict__ Wl2, const float* __restrict__ bl2,
                      const float* __restrict__ Wl3, const float* __restrict__ bl3,
                      float* __restrict__ out) {
    __shared__ float p[100], q[100];
    int g = blockIdx.x, t = threadIdx.x;
    if (t < 100) p[t] = pooled[g * 100 + t];
    __syncthreads();
    float s1 = 0.f;
    if (t < 100) {
        s1 = bl1[t];
        for (int k = 0; k < 100; k++) s1 += p[k] * Wl1[k * 100 + t];
        s1 = fmaxf(s1, 0.f);
    }
    __syncthreads();
    if (t < 100) q[t] = s1;
    __syncthreads();
    float s2 = 0.f;
    if (t < 100) {
        s2 = bl2[t];
        for (int k = 0; k < 100; k++) s2 += q[k] * Wl2[k * 100 + t];
        s2 = fmaxf(s2, 0.f);
    }
    __syncthreads();
    if (t < 100) p[t] = s2;
    __syncthreads();
    if (t < 29) {
        float s3 = bl3[t];
        for (int k = 0; k < 100; k++) s3 += p[k] * Wl3[k * 29 + t];
        out[g * 29 + t] = s3;
    }
}

// ---------------- launch ----------------
extern "C" void kernel_launch(void* const* d_in, const int* in_sizes, int n_in,
                              void* d_out, int out_size, void* d_ws, size_t ws_size,
                              hipStream_t stream) {
    const float* x     = (const float*)d_in[0];
    const int*   ei    = (const int*)d_in[1];
    const int*   batch = (const int*)d_in[2];
    const float* W1 = (const float*)d_in[3];  const float* b1 = (const float*)d_in[4];
    const float* W2 = (const float*)d_in[5];  const float* b2 = (const float*)d_in[6];
    const float* W3 = (const float*)d_in[7];  const float* b3 = (const float*)d_in[8];
    const float* W4 = (const float*)d_in[9];  const float* b4 = (const float*)d_in[10];
    const float* W5 = (const float*)d_in[11]; const float* b5 = (const float*)d_in[12];
    const float* Wl1 = (const float*)d_in[13]; const float* bl1 = (const float*)d_in[14];
    const float* Wl2 = (const float*)d_in[15]; const float* bl2 = (const float*)d_in[16];
    const float* Wl3 = (const float*)d_in[17]; const float* bl3 = (const float*)d_in[18];
    float* out = (float*)d_out;

    const int* row = ei;
    const int* col = ei + NE;

    uintptr_t base = (uintptr_t)d_ws;
    auto alloc = [&](size_t bytes) -> void* {
        void* p = (void*)base;
        base += (bytes + 255) & ~(size_t)255;
        return p;
    };
    int*   degcnt = (int*)alloc(NN * 4);
    float* dinv   = (float*)alloc(NN * 4);
    int*   indptr = (int*)alloc((NN + 1) * 4);
    int*   fill   = (int*)alloc(NN * 4);
    int*   csum   = (int*)alloc(512 * 4);
    int*   csum2  = (int*)alloc(512 * 4);
    int*   gcnt   = (int*)alloc(1024 * 4);
    int*   gstart = (int*)alloc(1024 * 4);
    int*   esrc   = (int*)alloc((size_t)NE * 4);
    float* ew     = (float*)alloc((size_t)NE * 4);
    float* xw     = (float*)alloc((size_t)NN * LDA * 4);
    float* h      = (float*)alloc((size_t)NN * LDA * 4);
    float* pooled = (float*)alloc((size_t)NG * 100 * 4);
    unsigned short* w1hi = (unsigned short*)alloc((size_t)112 * 384 * 2);
    unsigned short* w1lo = (unsigned short*)alloc((size_t)112 * 384 * 2);
    unsigned short* w2hi = (unsigned short*)alloc((size_t)112 * 128 * 2);
    unsigned short* w2lo = (unsigned short*)alloc((size_t)112 * 128 * 2);
    unsigned short* w3hi = (unsigned short*)alloc((size_t)112 * 128 * 2);
    unsigned short* w3lo = (unsigned short*)alloc((size_t)112 * 128 * 2);
    unsigned short* w4hi = (unsigned short*)alloc((size_t)112 * 128 * 2);
    unsigned short* w4lo = (unsigned short*)alloc((size_t)112 * 128 * 2);
    unsigned short* w5hi = (unsigned short*)alloc((size_t)112 * 128 * 2);
    unsigned short* w5lo = (unsigned short*)alloc((size_t)112 * 128 * 2);

    hipMemsetAsync(degcnt, 0, NN * 4, stream);
    hipMemsetAsync(fill, 0, NN * 4, stream);
    hipMemsetAsync(gcnt, 0, 1024 * 4, stream);

    const int NB = (NN + 255) / 256;  // 391
    k_deg<<<(NE + 255) / 256, 256, 0, stream>>>(col, degcnt);
    k_dinv<<<NB, 256, 0, stream>>>(degcnt, dinv);
    k_scan1<<<NB, 256, 0, stream>>>(degcnt, csum);
    k_scan2<<<1, 512, 0, stream>>>(csum, csum2, NB);
    k_scan3<<<NB, 256, 0, stream>>>(degcnt, csum2, indptr);
    k_scatter<<<(NE + 255) / 256, 256, 0, stream>>>(row, col, dinv, indptr, fill, esrc, ew);

    k_convW<<<(112 * 384 + 255) / 256, 256, 0, stream>>>(W1, w1hi, w1lo, 336, 384);
    k_convW<<<(112 * 128 + 255) / 256, 256, 0, stream>>>(W2, w2hi, w2lo, 100, 128);
    k_convW<<<(112 * 128 + 255) / 256, 256, 0, stream>>>(W3, w3hi, w3lo, 100, 128);
    k_convW<<<(112 * 128 + 255) / 256, 256, 0, stream>>>(W4, w4hi, w4lo, 100, 128);
    k_convW<<<(112 * 128 + 255) / 256, 256, 0, stream>>>(W5, w5hi, w5lo, 100, 128);

    const int GEMM_GRID = (NN + 63) / 64;  // 1563
    const int AGG_GRID = (NN + 3) / 4;     // 25000

    k_gemm3<<<GEMM_GRID, 256, 0, stream>>>(x, w1hi, w1lo, xw, NN, 336, 384, 336);
    k_agg<<<AGG_GRID, 256, 0, stream>>>(xw, indptr, esrc, ew, dinv, b1, h);
    k_gemm3<<<GEMM_GRID, 256, 0, stream>>>(h, w2hi, w2lo, xw, NN, 100, 128, LDA);
    k_agg<<<AGG_GRID, 256, 0, stream>>>(xw, indptr, esrc, ew, dinv, b2, h);
    k_gemm3<<<GEMM_GRID, 256, 0, stream>>>(h, w3hi, w3lo, xw, NN, 100, 128, LDA);
    k_agg<<<AGG_GRID, 256, 0, stream>>>(xw, indptr, esrc, ew, dinv, b3, h);
    k_gemm3<<<GEMM_GRID, 256, 0, stream>>>(h, w4hi, w4lo, xw, NN, 100, 128, LDA);
    k_agg<<<AGG_GRID, 256, 0, stream>>>(xw, indptr, esrc, ew, dinv, b4, h);
    k_gemm3<<<GEMM_GRID, 256, 0, stream>>>(h, w5hi, w5lo, xw, NN, 100, 128, LDA);
    k_agg<<<AGG_GRID, 256, 0, stream>>>(xw, indptr, esrc, ew, dinv, b5, h);

    k_gcount<<<NB, 256, 0, stream>>>(batch, gcnt);
    k_gscan<<<1, 1024, 0, stream>>>(gcnt, gstart);
    k_pool<<<NG, 128, 0, stream>>>(h, gcnt, gstart, pooled);
    k_mlp<<<NG, 128, 0, stream>>>(pooled, Wl1, bl1, Wl2, bl2, Wl3, bl3, out);
}